// Round 4
// baseline (401.663 us; speedup 1.0000x reference)
//
#include <hip/hip_runtime.h>
#include <hip/hip_bf16.h>

#define N_NODES 50000
#define N_EDGES 500000
#define E_AUG   (N_EDGES + N_NODES)   // 550000 (divisible by 4)
#define NH1 4
#define HID 64
#define C2  64

typedef unsigned int uint32;
typedef unsigned short ushort16;

__device__ __forceinline__ ushort16 f2bf(float f) {
    union { float f; uint32 u; } v; v.f = f;
    uint32 u = v.u + (0x7FFFu + ((v.u >> 16) & 1u));   // RNE
    return (ushort16)(u >> 16);
}
__device__ __forceinline__ float bf2f(ushort16 h) {
    union { uint32 u; float f; } v; v.u = ((uint32)h) << 16;
    return v.f;
}

// ---------------- weight packing ----------------
// Wpack[c][h][8] = {Wl0,Wl1,Wr0,Wr1,We0,We1, b1l+b1r, 0.4*att1} for column hc=h*64+c
// Apack[h][8]    = 0.6 * sum_c att1[h,c] * {Wl0,Wl1,Wr0,Wr1,We0,We1, bias} (lrelu linear part)

__global__ void pack_kernel(const float* __restrict__ W1l, const float* __restrict__ b1l,
                            const float* __restrict__ W1r, const float* __restrict__ b1r,
                            const float* __restrict__ W1e, const float* __restrict__ att1,
                            float* __restrict__ Wpack, float* __restrict__ Apack) {
    int t = threadIdx.x;
    if (t < 256) {
        int h = t >> 6, c = t & 63, hc = t;
        float* wp = &Wpack[(c * 4 + h) * 8];
        wp[0] = W1l[hc];       wp[1] = W1l[256 + hc];
        wp[2] = W1r[hc];       wp[3] = W1r[256 + hc];
        wp[4] = W1e[hc];       wp[5] = W1e[256 + hc];
        wp[6] = b1l[hc] + b1r[hc];
        wp[7] = 0.4f * att1[hc];
    }
    if (t < 28) {
        int h = t / 7, comp = t % 7;
        float s = 0.0f;
        for (int c = 0; c < 64; ++c) {
            int hc = h * 64 + c;
            float m;
            switch (comp) {
                case 0: m = W1l[hc]; break;
                case 1: m = W1l[256 + hc]; break;
                case 2: m = W1r[hc]; break;
                case 3: m = W1r[256 + hc]; break;
                case 4: m = W1e[hc]; break;
                case 5: m = W1e[256 + hc]; break;
                default: m = b1l[hc] + b1r[hc]; break;
            }
            s += att1[hc] * m;
        }
        Apack[h * 8 + comp] = 0.6f * s;
    }
}

// ---------------- CSR build ----------------

__global__ void deg_loop_kernel(const int* __restrict__ ei, const float* __restrict__ ea,
                                int* __restrict__ deg, float* __restrict__ lsum) {
    int e = blockIdx.x * 256 + threadIdx.x;
    if (e >= N_EDGES) return;
    int d = ei[N_EDGES + e];
    atomicAdd(&deg[d], 1);
    atomicAdd(&lsum[2 * d + 0], ea[2 * e + 0]);
    atomicAdd(&lsum[2 * d + 1], ea[2 * e + 1]);
}

__global__ void scan1_kernel(const int* __restrict__ deg, int* __restrict__ offs,
                             int* __restrict__ bsum) {
    __shared__ int s[256];
    int tid = threadIdx.x;
    int i = blockIdx.x * 256 + tid;
    int v = (i < N_NODES) ? (deg[i] + 1) : 0;   // +1 self loop
    s[tid] = v;
    __syncthreads();
    for (int off = 1; off < 256; off <<= 1) {
        int t = (tid >= off) ? s[tid - off] : 0;
        __syncthreads();
        s[tid] += t;
        __syncthreads();
    }
    if (i < N_NODES) offs[i + 1] = s[tid];
    if (tid == 255) bsum[blockIdx.x] = s[255];
}

// merged scan2+scan3: each block reduces bsum[j<blockIdx] and applies
__global__ void scan23_kernel(int* __restrict__ offs, const int* __restrict__ bsum, int nb) {
    __shared__ int s[256];
    int tid = threadIdx.x;
    int b = blockIdx.x;
    s[tid] = (tid < nb && tid < b) ? bsum[tid] : 0;
    __syncthreads();
    for (int off = 128; off; off >>= 1) {
        if (tid < off) s[tid] += s[tid + off];
        __syncthreads();
    }
    int base = s[0];
    int i = b * 256 + tid;
    if (i < N_NODES) offs[i + 1] += base;
    if (i == 0) offs[0] = 0;
}

__global__ void scatter_kernel(const int* __restrict__ ei, const float* __restrict__ ea,
                               const int* __restrict__ deg, const float* __restrict__ lsum,
                               const int* __restrict__ offs, int* __restrict__ cnt,
                               int* __restrict__ e_src, int* __restrict__ e_dst,
                               float* __restrict__ e_ea) {
    int e = blockIdx.x * 256 + threadIdx.x;
    if (e >= E_AUG) return;
    int s, d; float a0, a1;
    if (e < N_EDGES) {
        s = ei[e]; d = ei[N_EDGES + e];
        a0 = ea[2 * e + 0]; a1 = ea[2 * e + 1];
    } else {
        int n = e - N_EDGES;
        s = n; d = n;
        float dg = (float)max(deg[n], 1);
        a0 = lsum[2 * n + 0] / dg;
        a1 = lsum[2 * n + 1] / dg;
    }
    int pos = offs[d] + atomicAdd(&cnt[d], 1);
    e_src[pos] = s;
    e_dst[pos] = d;
    e_ea[2 * pos + 0] = a0;
    e_ea[2 * pos + 1] = a1;
}

// ---------------- Layer 1 alpha: edge-parallel, 4 edges/thread ----------------
// p_h = A_h·[u,1] + sum_c 0.4*att_hc*|z_hc|,  z = W·u + b   (lrelu = 0.6z + 0.4|z|)
// alpha1 stored SoA: plane h at alpha1[h*E_AUG + e]

__global__ __launch_bounds__(256) void l1_alpha_kernel(
    const float* __restrict__ x, const int* __restrict__ e_src,
    const int* __restrict__ e_dst, const float* __restrict__ e_ea,
    const float* __restrict__ Wpack, const float* __restrict__ Apack,
    float* __restrict__ alpha1) {
    __shared__ float sWp[2048];
    __shared__ float sA[32];
    const int tid = threadIdx.x;
    for (int i = tid; i < 2048; i += 256) sWp[i] = Wpack[i];
    if (tid < 32) sA[tid] = Apack[tid];
    __syncthreads();

    const int e0 = (blockIdx.x * 256 + tid) * 4;
    if (e0 >= E_AUG) return;   // E_AUG % 4 == 0 -> full quads only

    const int4 s4 = *(const int4*)&e_src[e0];
    const int4 d4 = *(const int4*)&e_dst[e0];
    const float4 ea0 = *(const float4*)&e_ea[2 * e0];
    const float4 ea1 = *(const float4*)&e_ea[2 * e0 + 4];

    float u0[4], u1[4], u2[4], u3[4], u4[4], u5[4];
    {
        const int ss[4] = {s4.x, s4.y, s4.z, s4.w};
        const int dd[4] = {d4.x, d4.y, d4.z, d4.w};
        const float ae[8] = {ea0.x, ea0.y, ea0.z, ea0.w, ea1.x, ea1.y, ea1.z, ea1.w};
        #pragma unroll
        for (int j = 0; j < 4; ++j) {
            float2 xs = *(const float2*)&x[2 * ss[j]];
            float2 xd = *(const float2*)&x[2 * dd[j]];
            u0[j] = xs.x; u1[j] = xs.y; u2[j] = xd.x; u3[j] = xd.y;
            u4[j] = ae[2 * j]; u5[j] = ae[2 * j + 1];
        }
    }

    float p[4][4];
    #pragma unroll
    for (int h = 0; h < 4; ++h) {
        const float a0 = sA[h * 8], a1 = sA[h * 8 + 1], a2 = sA[h * 8 + 2],
                    a3 = sA[h * 8 + 3], a4 = sA[h * 8 + 4], a5 = sA[h * 8 + 5],
                    a6 = sA[h * 8 + 6];
        #pragma unroll
        for (int j = 0; j < 4; ++j)
            p[h][j] = fmaf(u0[j], a0, fmaf(u1[j], a1, fmaf(u2[j], a2,
                      fmaf(u3[j], a3, fmaf(u4[j], a4, fmaf(u5[j], a5, a6))))));
    }

    for (int c = 0; c < 64; ++c) {
        const float* wp = &sWp[c * 32];
        #pragma unroll
        for (int h = 0; h < 4; ++h) {
            const float4 wa = *(const float4*)&wp[h * 8];
            const float4 wb = *(const float4*)&wp[h * 8 + 4];
            #pragma unroll
            for (int j = 0; j < 4; ++j) {
                float t = fmaf(u0[j], wa.x,
                          fmaf(u1[j], wa.y,
                          fmaf(u2[j], wa.z,
                          fmaf(u3[j], wa.w,
                          fmaf(u4[j], wb.x,
                          fmaf(u5[j], wb.y, wb.z))))));
                p[h][j] = fmaf(fabsf(t), wb.w, p[h][j]);
            }
        }
    }

    #pragma unroll
    for (int h = 0; h < 4; ++h)
        *(float4*)&alpha1[h * E_AUG + e0] = make_float4(p[h][0], p[h][1], p[h][2], p[h][3]);
}

// ---------------- Layer 1: online softmax, thread per (node,head) ----------------
// Sbuf[n][0..3] = sum_e w_eh*x[s].x / den ; Sbuf[n][4..7] = sum_e w_eh*x[s].y / den

__global__ __launch_bounds__(256) void l1_softmax_kernel(
    const float* __restrict__ x, const int* __restrict__ offs,
    const int* __restrict__ e_src, const float* __restrict__ alpha1,
    float* __restrict__ Sbuf) {
    int t = blockIdx.x * 256 + threadIdx.x;
    if (t >= 4 * N_NODES) return;
    int n = t >> 2, h = t & 3;
    int beg = offs[n], end = offs[n + 1];
    const float* ap = alpha1 + (size_t)h * E_AUG;

    float amax = -1e30f, den = 0.0f, s1 = 0.0f, s2 = 0.0f;
    for (int e = beg; e < end; ++e) {
        float lg = ap[e];
        int s = e_src[e];
        float2 xs = *(const float2*)&x[2 * s];
        float m = fmaxf(amax, lg);
        float sc = __expf(amax - m);
        float w = __expf(lg - m);
        den = fmaf(den, sc, w);
        s1 = fmaf(s1, sc, w * xs.x);
        s2 = fmaf(s2, sc, w * xs.y);
        amax = m;
    }
    float inv = 1.0f / (den + 1e-16f);
    Sbuf[n * 8 + h] = s1 * inv;
    Sbuf[n * 8 + 4 + h] = s2 * inv;
}

// ---------------- Layer 1 output tile (LDS) + layer 2 projections (bf16 out) ----------------
// h[n,hc] = elu(Wl0[hc]*S1[n,h] + Wl1[hc]*S2[n,h] + b1l[hc] + bias1[hc])
// xl2 = h@W2l + b2l ; xr2 = h@W2r + b2r  -> bf16
// thread map (GEMM phase): c2 = tid&31 (col pair 2c2,2c2+1), g = tid>>5 (node group of 4)

__global__ __launch_bounds__(256) void l1out_gemm_kernel(
    const float* __restrict__ Sbuf,
    const float* __restrict__ W1l, const float* __restrict__ b1l,
    const float* __restrict__ bias1,
    const float* __restrict__ W2l, const float* __restrict__ b2l,
    const float* __restrict__ W2r, const float* __restrict__ b2r,
    ushort16* __restrict__ xl2b, ushort16* __restrict__ xr2b) {
    __shared__ float sS[32][8];
    __shared__ float hs[32][256];
    const int tid = threadIdx.x;
    const int n0 = blockIdx.x * 32;
    {
        int idx = n0 * 8 + tid;
        sS[tid >> 3][tid & 7] = (idx < N_NODES * 8) ? Sbuf[idx] : 0.0f;
    }
    __syncthreads();

    {   // build h tile: thread = column hc, all 32 nodes
        const int c = tid, h = c >> 6;
        const float wl0 = W1l[c], wl1 = W1l[256 + c];
        const float bs = b1l[c] + bias1[c];
        #pragma unroll 4
        for (int n = 0; n < 32; ++n) {
            float g = fmaf(wl0, sS[n][h], fmaf(wl1, sS[n][4 + h], bs));
            hs[n][c] = g > 0.0f ? g : expm1f(g);
        }
    }
    __syncthreads();

    const int c2 = tid & 31, g = tid >> 5;
    const int c0 = c2 * 2;
    float acc[4][4];   // [node j][L0,L1,R0,R1]
    #pragma unroll
    for (int j = 0; j < 4; ++j)
        #pragma unroll
        for (int q = 0; q < 4; ++q) acc[j][q] = 0.0f;

    for (int k = 0; k < 256; k += 4) {
        float2 wl[4], wr[4];
        #pragma unroll
        for (int kk = 0; kk < 4; ++kk) {
            wl[kk] = *(const float2*)&W2l[(k + kk) * 64 + c0];
            wr[kk] = *(const float2*)&W2r[(k + kk) * 64 + c0];
        }
        #pragma unroll
        for (int j = 0; j < 4; ++j) {
            const float4 hv = *(const float4*)&hs[g * 4 + j][k];
            const float hh[4] = {hv.x, hv.y, hv.z, hv.w};
            #pragma unroll
            for (int kk = 0; kk < 4; ++kk) {
                acc[j][0] = fmaf(hh[kk], wl[kk].x, acc[j][0]);
                acc[j][1] = fmaf(hh[kk], wl[kk].y, acc[j][1]);
                acc[j][2] = fmaf(hh[kk], wr[kk].x, acc[j][2]);
                acc[j][3] = fmaf(hh[kk], wr[kk].y, acc[j][3]);
            }
        }
    }

    const float2 bl2 = *(const float2*)&b2l[c0];
    const float2 br2 = *(const float2*)&b2r[c0];
    #pragma unroll
    for (int j = 0; j < 4; ++j) {
        int n = n0 + g * 4 + j;
        if (n < N_NODES) {
            uint32 pl = ((uint32)f2bf(acc[j][1] + bl2.y) << 16) | f2bf(acc[j][0] + bl2.x);
            uint32 pr = ((uint32)f2bf(acc[j][3] + br2.y) << 16) | f2bf(acc[j][2] + br2.x);
            ((uint32*)xl2b)[n * 32 + c2] = pl;
            ((uint32*)xr2b)[n * 32 + c2] = pr;
        }
    }
}

// ---------------- Layer 2: online-softmax GATv2 (H=1, C=64), partial-sum out ----------------

__global__ __launch_bounds__(256) void l2_fused_kernel(
    const ushort16* __restrict__ xl2b, const ushort16* __restrict__ xr2b,
    const int* __restrict__ offs, const int* __restrict__ e_src,
    const float* __restrict__ e_ea,
    const float* __restrict__ W2e, const float* __restrict__ att2,
    float* __restrict__ pblock) {
    __shared__ float sWe[128], satt[64];
    __shared__ float sp[4][64];
    int tid = threadIdx.x;
    if (tid < 128) sWe[tid] = W2e[tid];
    if (tid < 64) satt[tid] = att2[tid];
    __syncthreads();

    const int l = tid & 63;
    const int w = tid >> 6;
    const int n = blockIdx.x * 4 + w;

    const float xr = bf2f(xr2b[n * C2 + l]);
    const float we0 = sWe[l], we1 = sWe[64 + l], at = satt[l];
    int beg = offs[n], end = offs[n + 1];

    float amax = -1e30f, den = 0.0f, acc = 0.0f;
    for (int e = beg; e < end; ++e) {
        int s = e_src[e];
        const float2 ae = *(const float2*)&e_ea[2 * e];
        float xl = bf2f(xl2b[s * C2 + l]);
        float t = xl + xr + fmaf(ae.x, we0, ae.y * we1);
        t = t > 0.0f ? t : 0.2f * t;
        float p = t * at;
        #pragma unroll
        for (int off = 32; off; off >>= 1) p += __shfl_xor(p, off);
        float mnew = fmaxf(amax, p);
        float sc = __expf(amax - mnew);
        float ww = __expf(p - mnew);
        den = fmaf(den, sc, ww);
        acc = fmaf(acc, sc, ww * xl);
        amax = mnew;
    }
    sp[w][l] = acc / (den + 1e-16f);
    __syncthreads();
    if (tid < 64) {
        float v = sp[0][l] + sp[1][l] + sp[2][l] + sp[3][l];
        pblock[blockIdx.x * 64 + l] = v;
    }
}

// ---------------- final pool: reduce 12500 block partials + bias ----------------

__global__ __launch_bounds__(256) void pool_final_kernel(const float* __restrict__ pblock,
                                                         const float* __restrict__ bias2,
                                                         float* __restrict__ d_out) {
    __shared__ float s[256];
    int tid = threadIdx.x;
    int l = tid & 63, q = tid >> 6;
    float local = 0.0f;
    for (int r = blockIdx.x * 4 + q; r < 12500; r += 64 * 4)
        local += pblock[r * 64 + l];
    s[tid] = local;
    __syncthreads();
    if (tid < 64) {
        float v = s[tid] + s[tid + 64] + s[tid + 128] + s[tid + 192];
        atomicAdd(&d_out[tid], v * (1.0f / N_NODES));
        if (blockIdx.x == 0) atomicAdd(&d_out[tid], bias2[tid]);
    }
}

// ---------------- Host launch ----------------

extern "C" void kernel_launch(void* const* d_in, const int* in_sizes, int n_in,
                              void* d_out, int out_size, void* d_ws, size_t ws_size,
                              hipStream_t stream) {
    const float* x     = (const float*)d_in[0];
    const float* eattr = (const float*)d_in[1];
    const float* W1l   = (const float*)d_in[2];
    const float* b1l   = (const float*)d_in[3];
    const float* W1r   = (const float*)d_in[4];
    const float* b1r   = (const float*)d_in[5];
    const float* W1e   = (const float*)d_in[6];
    const float* att1  = (const float*)d_in[7];
    const float* bias1 = (const float*)d_in[8];
    const float* W2l   = (const float*)d_in[9];
    const float* b2l   = (const float*)d_in[10];
    const float* W2r   = (const float*)d_in[11];
    const float* b2r   = (const float*)d_in[12];
    const float* W2e   = (const float*)d_in[13];
    const float* att2  = (const float*)d_in[14];
    const float* bias2 = (const float*)d_in[15];
    const int*   ei    = (const int*)d_in[16];
    float* out = (float*)d_out;

    char* p = (char*)d_ws;
    auto alloc = [&](size_t bytes) -> void* {
        void* r = (void*)p;
        p += (bytes + 255) & ~(size_t)255;
        return r;
    };
    // deg, cnt, lsum contiguous -> one memset
    int*   deg    = (int*)alloc(N_NODES * 4);
    int*   cnt    = (int*)alloc(N_NODES * 4);
    float* lsum   = (float*)alloc(N_NODES * 2 * 4);
    size_t zlen   = (size_t)((char*)lsum - (char*)deg) + ((N_NODES * 2 * 4 + 255) & ~(size_t)255);
    int*   offs   = (int*)alloc((N_NODES + 1) * 4);
    int*   bsum   = (int*)alloc(256 * 4);
    int*   e_src  = (int*)alloc(E_AUG * 4);
    int*   e_dst  = (int*)alloc(E_AUG * 4);
    float* e_ea   = (float*)alloc((size_t)E_AUG * 2 * 4);
    float* alpha1 = (float*)alloc((size_t)E_AUG * 4 * 4);
    float* Sbuf   = (float*)alloc((size_t)N_NODES * 8 * 4);
    float* Wpack  = (float*)alloc(256 * 8 * 4);
    float* Apack  = (float*)alloc(32 * 4);
    ushort16* xl2b = (ushort16*)alloc((size_t)N_NODES * C2 * 2);
    ushort16* xr2b = (ushort16*)alloc((size_t)N_NODES * C2 * 2);
    float* pblock = (float*)alloc((size_t)12500 * 64 * 4);

    hipMemsetAsync(deg, 0, zlen, stream);
    hipMemsetAsync(d_out, 0, 64 * 4, stream);

    pack_kernel<<<1, 256, 0, stream>>>(W1l, b1l, W1r, b1r, W1e, att1, Wpack, Apack);

    deg_loop_kernel<<<(N_EDGES + 255) / 256, 256, 0, stream>>>(ei, eattr, deg, lsum);
    int nb = (N_NODES + 255) / 256;   // 196
    scan1_kernel<<<nb, 256, 0, stream>>>(deg, offs, bsum);
    scan23_kernel<<<nb, 256, 0, stream>>>(offs, bsum, nb);
    scatter_kernel<<<(E_AUG + 255) / 256, 256, 0, stream>>>(ei, eattr, deg, lsum, offs, cnt,
                                                            e_src, e_dst, e_ea);

    l1_alpha_kernel<<<(E_AUG / 4 + 255) / 256, 256, 0, stream>>>(x, e_src, e_dst, e_ea,
                                                                 Wpack, Apack, alpha1);

    l1_softmax_kernel<<<(4 * N_NODES + 255) / 256, 256, 0, stream>>>(x, offs, e_src,
                                                                     alpha1, Sbuf);

    l1out_gemm_kernel<<<(N_NODES + 31) / 32, 256, 0, stream>>>(Sbuf, W1l, b1l, bias1,
                                                               W2l, b2l, W2r, b2r, xl2b, xr2b);

    l2_fused_kernel<<<N_NODES / 4, 256, 0, stream>>>(xl2b, xr2b, offs, e_src, e_ea,
                                                     W2e, att2, pblock);

    pool_final_kernel<<<64, 256, 0, stream>>>(pblock, bias2, out);
}

// Round 5
// 339.817 us; speedup vs baseline: 1.1820x; 1.1820x over previous
//
#include <hip/hip_runtime.h>
#include <hip/hip_bf16.h>

#define N_NODES 50000
#define N_EDGES 500000
#define E_AUG   (N_EDGES + N_NODES)   // 550000 (divisible by 4)
#define NH1 4
#define HID 64
#define C2  64
#define HS_LD 72                       // padded row stride for hsch

typedef unsigned int uint32;
typedef unsigned short ushort16;

__device__ __forceinline__ ushort16 f2bf(float f) {
    union { float f; uint32 u; } v; v.f = f;
    uint32 u = v.u + (0x7FFFu + ((v.u >> 16) & 1u));   // RNE
    return (ushort16)(u >> 16);
}
__device__ __forceinline__ float bf2f(ushort16 h) {
    union { uint32 u; float f; } v; v.u = ((uint32)h) << 16;
    return v.f;
}

// ---------------- weight packing ----------------
// Wpack[c][h][8] = {Wl0,Wl1,Wr0,Wr1,We0,We1, b1l+b1r, 0.4*att1} for column hc=h*64+c
// Apack[h][8]    = 0.6 * sum_c att1[h,c] * {Wl0,Wl1,Wr0,Wr1,We0,We1, bias} (lrelu linear part)

__global__ void pack_kernel(const float* __restrict__ W1l, const float* __restrict__ b1l,
                            const float* __restrict__ W1r, const float* __restrict__ b1r,
                            const float* __restrict__ W1e, const float* __restrict__ att1,
                            float* __restrict__ Wpack, float* __restrict__ Apack) {
    int t = threadIdx.x;
    if (t < 256) {
        int h = t >> 6, c = t & 63, hc = t;
        float* wp = &Wpack[(c * 4 + h) * 8];
        wp[0] = W1l[hc];       wp[1] = W1l[256 + hc];
        wp[2] = W1r[hc];       wp[3] = W1r[256 + hc];
        wp[4] = W1e[hc];       wp[5] = W1e[256 + hc];
        wp[6] = b1l[hc] + b1r[hc];
        wp[7] = 0.4f * att1[hc];
    }
    if (t < 28) {
        int h = t / 7, comp = t % 7;
        float s = 0.0f;
        for (int c = 0; c < 64; ++c) {
            int hc = h * 64 + c;
            float m;
            switch (comp) {
                case 0: m = W1l[hc]; break;
                case 1: m = W1l[256 + hc]; break;
                case 2: m = W1r[hc]; break;
                case 3: m = W1r[256 + hc]; break;
                case 4: m = W1e[hc]; break;
                case 5: m = W1e[256 + hc]; break;
                default: m = b1l[hc] + b1r[hc]; break;
            }
            s += att1[hc] * m;
        }
        Apack[h * 8 + comp] = 0.6f * s;
    }
}

// ---------------- CSR build ----------------

__global__ void deg_loop_kernel(const int* __restrict__ ei, const float* __restrict__ ea,
                                int* __restrict__ deg, float* __restrict__ lsum) {
    int e = blockIdx.x * 256 + threadIdx.x;
    if (e >= N_EDGES) return;
    int d = ei[N_EDGES + e];
    atomicAdd(&deg[d], 1);
    atomicAdd(&lsum[2 * d + 0], ea[2 * e + 0]);
    atomicAdd(&lsum[2 * d + 1], ea[2 * e + 1]);
}

__global__ void scan1_kernel(const int* __restrict__ deg, int* __restrict__ offs,
                             int* __restrict__ bsum) {
    __shared__ int s[256];
    int tid = threadIdx.x;
    int i = blockIdx.x * 256 + tid;
    int v = (i < N_NODES) ? (deg[i] + 1) : 0;   // +1 self loop
    s[tid] = v;
    __syncthreads();
    for (int off = 1; off < 256; off <<= 1) {
        int t = (tid >= off) ? s[tid - off] : 0;
        __syncthreads();
        s[tid] += t;
        __syncthreads();
    }
    if (i < N_NODES) offs[i + 1] = s[tid];
    if (tid == 255) bsum[blockIdx.x] = s[255];
}

// merged scan2+scan3: each block reduces bsum[j<blockIdx] and applies
__global__ void scan23_kernel(int* __restrict__ offs, const int* __restrict__ bsum, int nb) {
    __shared__ int s[256];
    int tid = threadIdx.x;
    int b = blockIdx.x;
    s[tid] = (tid < nb && tid < b) ? bsum[tid] : 0;
    __syncthreads();
    for (int off = 128; off; off >>= 1) {
        if (tid < off) s[tid] += s[tid + off];
        __syncthreads();
    }
    int base = s[0];
    int i = b * 256 + tid;
    if (i < N_NODES) offs[i + 1] += base;
    if (i == 0) offs[0] = 0;
}

__global__ void scatter_kernel(const int* __restrict__ ei, const float* __restrict__ ea,
                               const int* __restrict__ deg, const float* __restrict__ lsum,
                               const int* __restrict__ offs, int* __restrict__ cnt,
                               int* __restrict__ e_src, int* __restrict__ e_dst,
                               float* __restrict__ e_ea) {
    int e = blockIdx.x * 256 + threadIdx.x;
    if (e >= E_AUG) return;
    int s, d; float a0, a1;
    if (e < N_EDGES) {
        s = ei[e]; d = ei[N_EDGES + e];
        a0 = ea[2 * e + 0]; a1 = ea[2 * e + 1];
    } else {
        int n = e - N_EDGES;
        s = n; d = n;
        float dg = (float)max(deg[n], 1);
        a0 = lsum[2 * n + 0] / dg;
        a1 = lsum[2 * n + 1] / dg;
    }
    int pos = offs[d] + atomicAdd(&cnt[d], 1);
    e_src[pos] = s;
    e_dst[pos] = d;
    e_ea[2 * pos + 0] = a0;
    e_ea[2 * pos + 1] = a1;
}

// ---------------- Layer 1 alpha: edge-parallel, 4 edges/thread ----------------
// p_h = A_h·[u,1] + sum_c 0.4*att_hc*|z_hc|,  z = W·u + b   (lrelu = 0.6z + 0.4|z|)
// alpha1 stored SoA: plane h at alpha1[h*E_AUG + e]

__global__ __launch_bounds__(256) void l1_alpha_kernel(
    const float* __restrict__ x, const int* __restrict__ e_src,
    const int* __restrict__ e_dst, const float* __restrict__ e_ea,
    const float* __restrict__ Wpack, const float* __restrict__ Apack,
    float* __restrict__ alpha1) {
    __shared__ float sWp[2048];
    __shared__ float sA[32];
    const int tid = threadIdx.x;
    for (int i = tid; i < 2048; i += 256) sWp[i] = Wpack[i];
    if (tid < 32) sA[tid] = Apack[tid];
    __syncthreads();

    const int e0 = (blockIdx.x * 256 + tid) * 4;
    if (e0 >= E_AUG) return;   // E_AUG % 4 == 0 -> full quads only

    const int4 s4 = *(const int4*)&e_src[e0];
    const int4 d4 = *(const int4*)&e_dst[e0];
    const float4 ea0 = *(const float4*)&e_ea[2 * e0];
    const float4 ea1 = *(const float4*)&e_ea[2 * e0 + 4];

    float u0[4], u1[4], u2[4], u3[4], u4[4], u5[4];
    {
        const int ss[4] = {s4.x, s4.y, s4.z, s4.w};
        const int dd[4] = {d4.x, d4.y, d4.z, d4.w};
        const float ae[8] = {ea0.x, ea0.y, ea0.z, ea0.w, ea1.x, ea1.y, ea1.z, ea1.w};
        #pragma unroll
        for (int j = 0; j < 4; ++j) {
            float2 xs = *(const float2*)&x[2 * ss[j]];
            float2 xd = *(const float2*)&x[2 * dd[j]];
            u0[j] = xs.x; u1[j] = xs.y; u2[j] = xd.x; u3[j] = xd.y;
            u4[j] = ae[2 * j]; u5[j] = ae[2 * j + 1];
        }
    }

    float p[4][4];
    #pragma unroll
    for (int h = 0; h < 4; ++h) {
        const float a0 = sA[h * 8], a1 = sA[h * 8 + 1], a2 = sA[h * 8 + 2],
                    a3 = sA[h * 8 + 3], a4 = sA[h * 8 + 4], a5 = sA[h * 8 + 5],
                    a6 = sA[h * 8 + 6];
        #pragma unroll
        for (int j = 0; j < 4; ++j)
            p[h][j] = fmaf(u0[j], a0, fmaf(u1[j], a1, fmaf(u2[j], a2,
                      fmaf(u3[j], a3, fmaf(u4[j], a4, fmaf(u5[j], a5, a6))))));
    }

    for (int c = 0; c < 64; ++c) {
        const float* wp = &sWp[c * 32];
        #pragma unroll
        for (int h = 0; h < 4; ++h) {
            const float4 wa = *(const float4*)&wp[h * 8];
            const float4 wb = *(const float4*)&wp[h * 8 + 4];
            #pragma unroll
            for (int j = 0; j < 4; ++j) {
                float t = fmaf(u0[j], wa.x,
                          fmaf(u1[j], wa.y,
                          fmaf(u2[j], wa.z,
                          fmaf(u3[j], wa.w,
                          fmaf(u4[j], wb.x,
                          fmaf(u5[j], wb.y, wb.z))))));
                p[h][j] = fmaf(fabsf(t), wb.w, p[h][j]);
            }
        }
    }

    #pragma unroll
    for (int h = 0; h < 4; ++h)
        *(float4*)&alpha1[h * E_AUG + e0] = make_float4(p[h][0], p[h][1], p[h][2], p[h][3]);
}

// ---------------- Layer 1: online softmax, thread per (node,head) ----------------
// Sbuf[n][0..3] = sum_e w_eh*x[s].x / den ; Sbuf[n][4..7] = sum_e w_eh*x[s].y / den

__global__ __launch_bounds__(256) void l1_softmax_kernel(
    const float* __restrict__ x, const int* __restrict__ offs,
    const int* __restrict__ e_src, const float* __restrict__ alpha1,
    float* __restrict__ Sbuf) {
    int t = blockIdx.x * 256 + threadIdx.x;
    if (t >= 4 * N_NODES) return;
    int n = t >> 2, h = t & 3;
    int beg = offs[n], end = offs[n + 1];
    const float* ap = alpha1 + (size_t)h * E_AUG;

    float amax = -1e30f, den = 0.0f, s1 = 0.0f, s2 = 0.0f;
    for (int e = beg; e < end; ++e) {
        float lg = ap[e];
        int s = e_src[e];
        float2 xs = *(const float2*)&x[2 * s];
        float m = fmaxf(amax, lg);
        float sc = __expf(amax - m);
        float w = __expf(lg - m);
        den = fmaf(den, sc, w);
        s1 = fmaf(s1, sc, w * xs.x);
        s2 = fmaf(s2, sc, w * xs.y);
        amax = m;
    }
    float inv = 1.0f / (den + 1e-16f);
    Sbuf[n * 8 + h] = s1 * inv;
    Sbuf[n * 8 + 4 + h] = s2 * inv;
}

// ---------------- Layer 1 output + layer 2 projections, K-chunked LDS version ----
// 64 nodes/block. For each K-chunk of 64 (== one head):
//   stage W2l/W2r 64x64 tiles into LDS (coalesced float4, once per chunk)
//   rebuild h-tile hsch[64][64] in LDS from Sbuf (rank-2 + ELU)
//   FMA loop reads weights as conflict-free scalar LDS, h rows as broadcast b128.
// Outputs bf16 xl2b/xr2b.

__global__ __launch_bounds__(256) void l1out_gemm_kernel(
    const float* __restrict__ Sbuf,
    const float* __restrict__ W1l, const float* __restrict__ b1l,
    const float* __restrict__ bias1,
    const float* __restrict__ W2l, const float* __restrict__ b2l,
    const float* __restrict__ W2r, const float* __restrict__ b2r,
    ushort16* __restrict__ xl2b, ushort16* __restrict__ xr2b) {
    __shared__ float hsch[64][HS_LD];   // 18.4 KB
    __shared__ float sWL[64][64];       // 16 KB
    __shared__ float sWR[64][64];       // 16 KB
    const int tid = threadIdx.x;
    const int n0 = blockIdx.x * 64;

    const int c = tid & 63, q = tid >> 6;
    float accL[16], accR[16];
    #pragma unroll
    for (int j = 0; j < 16; ++j) { accL[j] = 0.0f; accR[j] = 0.0f; }

    const int bn = tid >> 2;            // build-phase node 0..63
    const int bg = tid & 3;             // build-phase col group
    const int node = n0 + bn;
    const bool nvalid = (node < N_NODES);

    for (int ch = 0; ch < 4; ++ch) {
        // ---- stage weight tiles (1024 float4 slots, 4 per thread) ----
        #pragma unroll
        for (int it = 0; it < 4; ++it) {
            int idx = tid + it * 256;
            int k = idx >> 4, cg = idx & 15;
            const float4 vl = *(const float4*)&W2l[(ch * 64 + k) * 64 + cg * 4];
            const float4 vr = *(const float4*)&W2r[(ch * 64 + k) * 64 + cg * 4];
            *(float4*)&sWL[k][cg * 4] = vl;
            *(float4*)&sWR[k][cg * 4] = vr;
        }
        // ---- build h chunk (head == ch) ----
        {
            float S1 = nvalid ? Sbuf[node * 8 + ch] : 0.0f;
            float S2 = nvalid ? Sbuf[node * 8 + 4 + ch] : 0.0f;
            #pragma unroll
            for (int i = 0; i < 4; ++i) {
                int cl0 = bg * 16 + i * 4;
                int hc0 = ch * 64 + cl0;
                const float4 wa = *(const float4*)&W1l[hc0];
                const float4 wb = *(const float4*)&W1l[256 + hc0];
                const float4 b1 = *(const float4*)&b1l[hc0];
                const float4 bb = *(const float4*)&bias1[hc0];
                float g0 = fmaf(wa.x, S1, fmaf(wb.x, S2, b1.x + bb.x));
                float g1 = fmaf(wa.y, S1, fmaf(wb.y, S2, b1.y + bb.y));
                float g2 = fmaf(wa.z, S1, fmaf(wb.z, S2, b1.z + bb.z));
                float g3 = fmaf(wa.w, S1, fmaf(wb.w, S2, b1.w + bb.w));
                float4 hv;
                hv.x = g0 > 0.0f ? g0 : expm1f(g0);
                hv.y = g1 > 0.0f ? g1 : expm1f(g1);
                hv.z = g2 > 0.0f ? g2 : expm1f(g2);
                hv.w = g3 > 0.0f ? g3 : expm1f(g3);
                *(float4*)&hsch[bn][cl0] = hv;
            }
        }
        __syncthreads();

        // ---- FMA loop over this K-chunk ----
        for (int kb = 0; kb < 64; kb += 4) {
            const float wl0 = sWL[kb + 0][c], wl1 = sWL[kb + 1][c],
                        wl2 = sWL[kb + 2][c], wl3 = sWL[kb + 3][c];
            const float wr0 = sWR[kb + 0][c], wr1 = sWR[kb + 1][c],
                        wr2 = sWR[kb + 2][c], wr3 = sWR[kb + 3][c];
            #pragma unroll
            for (int j = 0; j < 16; ++j) {
                const float4 hv = *(const float4*)&hsch[q * 16 + j][kb];
                accL[j] = fmaf(hv.x, wl0, fmaf(hv.y, wl1, fmaf(hv.z, wl2, fmaf(hv.w, wl3, accL[j]))));
                accR[j] = fmaf(hv.x, wr0, fmaf(hv.y, wr1, fmaf(hv.z, wr2, fmaf(hv.w, wr3, accR[j]))));
            }
        }
        __syncthreads();
    }

    const float bl = b2l[c], br = b2r[c];
    #pragma unroll
    for (int j = 0; j < 16; ++j) {
        int n = n0 + q * 16 + j;
        if (n < N_NODES) {
            xl2b[n * 64 + c] = f2bf(accL[j] + bl);
            xr2b[n * 64 + c] = f2bf(accR[j] + br);
        }
    }
}

// ---------------- Layer 2: online-softmax GATv2, 4-edge-unrolled butterflies ----

__global__ __launch_bounds__(256) void l2_fused_kernel(
    const ushort16* __restrict__ xl2b, const ushort16* __restrict__ xr2b,
    const int* __restrict__ offs, const int* __restrict__ e_src,
    const float* __restrict__ e_ea,
    const float* __restrict__ W2e, const float* __restrict__ att2,
    float* __restrict__ pblock) {
    __shared__ float sWe[128], satt[64];
    __shared__ float sp[4][64];
    int tid = threadIdx.x;
    if (tid < 128) sWe[tid] = W2e[tid];
    if (tid < 64) satt[tid] = att2[tid];
    __syncthreads();

    const int l = tid & 63;
    const int w = tid >> 6;
    const int n = blockIdx.x * 4 + w;

    const float xr = bf2f(xr2b[n * C2 + l]);
    const float we0 = sWe[l], we1 = sWe[64 + l], at = satt[l];
    const int beg = offs[n], end = offs[n + 1];

    float amax = -1e30f, den = 0.0f, acc = 0.0f;
    int e = beg;
    for (; e + 4 <= end; e += 4) {
        const int s0 = e_src[e], s1 = e_src[e + 1], s2 = e_src[e + 2], s3 = e_src[e + 3];
        const float2 a0 = *(const float2*)&e_ea[2 * e];
        const float2 a1 = *(const float2*)&e_ea[2 * e + 2];
        const float2 a2 = *(const float2*)&e_ea[2 * e + 4];
        const float2 a3 = *(const float2*)&e_ea[2 * e + 6];
        const float xla = bf2f(xl2b[s0 * C2 + l]);
        const float xlb = bf2f(xl2b[s1 * C2 + l]);
        const float xlc = bf2f(xl2b[s2 * C2 + l]);
        const float xld = bf2f(xl2b[s3 * C2 + l]);
        float t0 = xla + xr + fmaf(a0.x, we0, a0.y * we1);
        float t1 = xlb + xr + fmaf(a1.x, we0, a1.y * we1);
        float t2 = xlc + xr + fmaf(a2.x, we0, a2.y * we1);
        float t3 = xld + xr + fmaf(a3.x, we0, a3.y * we1);
        t0 = t0 > 0.0f ? t0 : 0.2f * t0;
        t1 = t1 > 0.0f ? t1 : 0.2f * t1;
        t2 = t2 > 0.0f ? t2 : 0.2f * t2;
        t3 = t3 > 0.0f ? t3 : 0.2f * t3;
        float p0 = t0 * at, p1 = t1 * at, p2 = t2 * at, p3 = t3 * at;
        #pragma unroll
        for (int off = 32; off; off >>= 1) {
            p0 += __shfl_xor(p0, off);
            p1 += __shfl_xor(p1, off);
            p2 += __shfl_xor(p2, off);
            p3 += __shfl_xor(p3, off);
        }
        const float mnew = fmaxf(fmaxf(amax, fmaxf(p0, p1)), fmaxf(p2, p3));
        const float sc = __expf(amax - mnew);
        const float w0 = __expf(p0 - mnew), w1 = __expf(p1 - mnew);
        const float w2 = __expf(p2 - mnew), w3 = __expf(p3 - mnew);
        den = fmaf(den, sc, (w0 + w1) + (w2 + w3));
        acc = fmaf(acc, sc, fmaf(w0, xla, fmaf(w1, xlb, fmaf(w2, xlc, w3 * xld))));
        amax = mnew;
    }
    for (; e < end; ++e) {
        const int s = e_src[e];
        const float2 ae = *(const float2*)&e_ea[2 * e];
        const float xl = bf2f(xl2b[s * C2 + l]);
        float t = xl + xr + fmaf(ae.x, we0, ae.y * we1);
        t = t > 0.0f ? t : 0.2f * t;
        float p = t * at;
        #pragma unroll
        for (int off = 32; off; off >>= 1) p += __shfl_xor(p, off);
        const float mnew = fmaxf(amax, p);
        const float sc = __expf(amax - mnew);
        const float ww = __expf(p - mnew);
        den = fmaf(den, sc, ww);
        acc = fmaf(acc, sc, ww * xl);
        amax = mnew;
    }
    sp[w][l] = acc / (den + 1e-16f);
    __syncthreads();
    if (tid < 64) {
        float v = sp[0][l] + sp[1][l] + sp[2][l] + sp[3][l];
        pblock[blockIdx.x * 64 + l] = v;
    }
}

// ---------------- final pool: reduce 12500 block partials + bias ----------------

__global__ __launch_bounds__(256) void pool_final_kernel(const float* __restrict__ pblock,
                                                         const float* __restrict__ bias2,
                                                         float* __restrict__ d_out) {
    __shared__ float s[256];
    int tid = threadIdx.x;
    int l = tid & 63, q = tid >> 6;
    float local = 0.0f;
    for (int r = blockIdx.x * 4 + q; r < 12500; r += 64 * 4)
        local += pblock[r * 64 + l];
    s[tid] = local;
    __syncthreads();
    if (tid < 64) {
        float v = s[tid] + s[tid + 64] + s[tid + 128] + s[tid + 192];
        atomicAdd(&d_out[tid], v * (1.0f / N_NODES));
        if (blockIdx.x == 0) atomicAdd(&d_out[tid], bias2[tid]);
    }
}

// ---------------- Host launch ----------------

extern "C" void kernel_launch(void* const* d_in, const int* in_sizes, int n_in,
                              void* d_out, int out_size, void* d_ws, size_t ws_size,
                              hipStream_t stream) {
    const float* x     = (const float*)d_in[0];
    const float* eattr = (const float*)d_in[1];
    const float* W1l   = (const float*)d_in[2];
    const float* b1l   = (const float*)d_in[3];
    const float* W1r   = (const float*)d_in[4];
    const float* b1r   = (const float*)d_in[5];
    const float* W1e   = (const float*)d_in[6];
    const float* att1  = (const float*)d_in[7];
    const float* bias1 = (const float*)d_in[8];
    const float* W2l   = (const float*)d_in[9];
    const float* b2l   = (const float*)d_in[10];
    const float* W2r   = (const float*)d_in[11];
    const float* b2r   = (const float*)d_in[12];
    const float* W2e   = (const float*)d_in[13];
    const float* att2  = (const float*)d_in[14];
    const float* bias2 = (const float*)d_in[15];
    const int*   ei    = (const int*)d_in[16];
    float* out = (float*)d_out;

    char* p = (char*)d_ws;
    auto alloc = [&](size_t bytes) -> void* {
        void* r = (void*)p;
        p += (bytes + 255) & ~(size_t)255;
        return r;
    };
    // deg, cnt, lsum contiguous -> one memset
    int*   deg    = (int*)alloc(N_NODES * 4);
    int*   cnt    = (int*)alloc(N_NODES * 4);
    float* lsum   = (float*)alloc(N_NODES * 2 * 4);
    size_t zlen   = (size_t)((char*)lsum - (char*)deg) + ((N_NODES * 2 * 4 + 255) & ~(size_t)255);
    int*   offs   = (int*)alloc((N_NODES + 1) * 4);
    int*   bsum   = (int*)alloc(256 * 4);
    int*   e_src  = (int*)alloc(E_AUG * 4);
    int*   e_dst  = (int*)alloc(E_AUG * 4);
    float* e_ea   = (float*)alloc((size_t)E_AUG * 2 * 4);
    float* alpha1 = (float*)alloc((size_t)E_AUG * 4 * 4);
    float* Sbuf   = (float*)alloc((size_t)N_NODES * 8 * 4);
    float* Wpack  = (float*)alloc(256 * 8 * 4);
    float* Apack  = (float*)alloc(32 * 4);
    ushort16* xl2b = (ushort16*)alloc((size_t)N_NODES * C2 * 2);
    ushort16* xr2b = (ushort16*)alloc((size_t)N_NODES * C2 * 2);
    float* pblock = (float*)alloc((size_t)12500 * 64 * 4);

    hipMemsetAsync(deg, 0, zlen, stream);
    hipMemsetAsync(d_out, 0, 64 * 4, stream);

    pack_kernel<<<1, 256, 0, stream>>>(W1l, b1l, W1r, b1r, W1e, att1, Wpack, Apack);

    deg_loop_kernel<<<(N_EDGES + 255) / 256, 256, 0, stream>>>(ei, eattr, deg, lsum);
    int nb = (N_NODES + 255) / 256;   // 196
    scan1_kernel<<<nb, 256, 0, stream>>>(deg, offs, bsum);
    scan23_kernel<<<nb, 256, 0, stream>>>(offs, bsum, nb);
    scatter_kernel<<<(E_AUG + 255) / 256, 256, 0, stream>>>(ei, eattr, deg, lsum, offs, cnt,
                                                            e_src, e_dst, e_ea);

    l1_alpha_kernel<<<(E_AUG / 4 + 255) / 256, 256, 0, stream>>>(x, e_src, e_dst, e_ea,
                                                                 Wpack, Apack, alpha1);

    l1_softmax_kernel<<<(4 * N_NODES + 255) / 256, 256, 0, stream>>>(x, offs, e_src,
                                                                     alpha1, Sbuf);

    l1out_gemm_kernel<<<(N_NODES + 63) / 64, 256, 0, stream>>>(Sbuf, W1l, b1l, bias1,
                                                               W2l, b2l, W2r, b2r, xl2b, xr2b);

    l2_fused_kernel<<<N_NODES / 4, 256, 0, stream>>>(xl2b, xr2b, offs, e_src, e_ea,
                                                     W2e, att2, pblock);

    pool_final_kernel<<<64, 256, 0, stream>>>(pblock, bias2, out);
}

// Round 6
// 308.781 us; speedup vs baseline: 1.3008x; 1.1005x over previous
//
#include <hip/hip_runtime.h>
#include <hip/hip_bf16.h>

#define N_NODES 50000
#define N_EDGES 500000
#define E_AUG   (N_EDGES + N_NODES)   // 550000 (divisible by 16)
#define NH1 4
#define HID 64
#define C2  64

typedef unsigned int uint32;
typedef unsigned short ushort16;
typedef __attribute__((ext_vector_type(8))) short short8v;
typedef __attribute__((ext_vector_type(4))) float f32x4;

__device__ __forceinline__ ushort16 f2bf(float f) {
    union { float f; uint32 u; } v; v.f = f;
    uint32 u = v.u + (0x7FFFu + ((v.u >> 16) & 1u));   // RNE
    return (ushort16)(u >> 16);
}
__device__ __forceinline__ float bf2f(ushort16 h) {
    union { uint32 u; float f; } v; v.u = ((uint32)h) << 16;
    return v.f;
}

// ---------------- weight packing ----------------
// Wpack[c][h][8] = {Wl0,Wl1,Wr0,Wr1,We0,We1, b1l+b1r, 0.4*att1} for column hc=h*64+c
// Apack[h][8]    = 0.6 * sum_c att1[h,c] * {...}  (lrelu linear part)
// wpk4[k]        = {W1l[0][k], W1l[1][k], b1l[k]+bias1[k], 0}  (h-build coeffs)
// Wt[c][k] bf16, c in [0,128): c<64 -> W2l[k][c], else W2r[k][c-64]  (B operand)

__global__ void pack_kernel(const float* __restrict__ W1l, const float* __restrict__ b1l,
                            const float* __restrict__ W1r, const float* __restrict__ b1r,
                            const float* __restrict__ W1e, const float* __restrict__ att1,
                            const float* __restrict__ bias1,
                            const float* __restrict__ W2l, const float* __restrict__ W2r,
                            float* __restrict__ Wpack, float* __restrict__ Apack,
                            float4* __restrict__ wpk4, ushort16* __restrict__ Wt) {
    int tid = threadIdx.x;
    int t = blockIdx.x * 256 + tid;
    if (blockIdx.x == 0) {
        if (tid < 256) {
            int h = tid >> 6, hc = tid;
            float* wp = &Wpack[((tid & 63) * 4 + h) * 8];
            wp[0] = W1l[hc];       wp[1] = W1l[256 + hc];
            wp[2] = W1r[hc];       wp[3] = W1r[256 + hc];
            wp[4] = W1e[hc];       wp[5] = W1e[256 + hc];
            wp[6] = b1l[hc] + b1r[hc];
            wp[7] = 0.4f * att1[hc];
            wpk4[hc] = make_float4(W1l[hc], W1l[256 + hc], b1l[hc] + bias1[hc], 0.0f);
        }
        if (tid < 28) {
            int h = tid / 7, comp = tid % 7;
            float s = 0.0f;
            for (int c = 0; c < 64; ++c) {
                int hc = h * 64 + c;
                float m;
                switch (comp) {
                    case 0: m = W1l[hc]; break;
                    case 1: m = W1l[256 + hc]; break;
                    case 2: m = W1r[hc]; break;
                    case 3: m = W1r[256 + hc]; break;
                    case 4: m = W1e[hc]; break;
                    case 5: m = W1e[256 + hc]; break;
                    default: m = b1l[hc] + b1r[hc]; break;
                }
                s += att1[hc] * m;
            }
            Apack[h * 8 + comp] = 0.6f * s;
        }
    }
    if (t < 128 * 256) {
        int c = t & 127, k = t >> 7;
        float w = (c < 64) ? W2l[k * 64 + c] : W2r[k * 64 + (c - 64)];
        Wt[c * 256 + k] = f2bf(w);
    }
}

// ---------------- CSR build ----------------

__global__ void deg_loop_kernel(const int* __restrict__ ei, const float* __restrict__ ea,
                                int* __restrict__ deg, float* __restrict__ lsum) {
    int e = blockIdx.x * 256 + threadIdx.x;
    if (e >= N_EDGES) return;
    int d = ei[N_EDGES + e];
    atomicAdd(&deg[d], 1);
    atomicAdd(&lsum[2 * d + 0], ea[2 * e + 0]);
    atomicAdd(&lsum[2 * d + 1], ea[2 * e + 1]);
}

__global__ void scan1_kernel(const int* __restrict__ deg, int* __restrict__ offs,
                             int* __restrict__ bsum) {
    __shared__ int s[256];
    int tid = threadIdx.x;
    int i = blockIdx.x * 256 + tid;
    int v = (i < N_NODES) ? (deg[i] + 1) : 0;   // +1 self loop
    s[tid] = v;
    __syncthreads();
    for (int off = 1; off < 256; off <<= 1) {
        int t = (tid >= off) ? s[tid - off] : 0;
        __syncthreads();
        s[tid] += t;
        __syncthreads();
    }
    if (i < N_NODES) offs[i + 1] = s[tid];
    if (tid == 255) bsum[blockIdx.x] = s[255];
}

__global__ void scan23_kernel(int* __restrict__ offs, const int* __restrict__ bsum, int nb) {
    __shared__ int s[256];
    int tid = threadIdx.x;
    int b = blockIdx.x;
    s[tid] = (tid < nb && tid < b) ? bsum[tid] : 0;
    __syncthreads();
    for (int off = 128; off; off >>= 1) {
        if (tid < off) s[tid] += s[tid + off];
        __syncthreads();
    }
    int base = s[0];
    int i = b * 256 + tid;
    if (i < N_NODES) offs[i + 1] += base;
    if (i == 0) offs[0] = 0;
}

__global__ void scatter_kernel(const int* __restrict__ ei, const float* __restrict__ ea,
                               const int* __restrict__ deg, const float* __restrict__ lsum,
                               const int* __restrict__ offs, int* __restrict__ cnt,
                               int* __restrict__ e_src, int* __restrict__ e_dst,
                               float* __restrict__ e_ea) {
    int e = blockIdx.x * 256 + threadIdx.x;
    if (e >= E_AUG) return;
    int s, d; float a0, a1;
    if (e < N_EDGES) {
        s = ei[e]; d = ei[N_EDGES + e];
        a0 = ea[2 * e + 0]; a1 = ea[2 * e + 1];
    } else {
        int n = e - N_EDGES;
        s = n; d = n;
        float dg = (float)max(deg[n], 1);
        a0 = lsum[2 * n + 0] / dg;
        a1 = lsum[2 * n + 1] / dg;
    }
    int pos = offs[d] + atomicAdd(&cnt[d], 1);
    e_src[pos] = s;
    e_dst[pos] = d;
    e_ea[2 * pos + 0] = a0;
    e_ea[2 * pos + 1] = a1;
}

// ---------------- Layer 1 alpha: edge-parallel, 4 edges/thread ----------------

__global__ __launch_bounds__(256) void l1_alpha_kernel(
    const float* __restrict__ x, const int* __restrict__ e_src,
    const int* __restrict__ e_dst, const float* __restrict__ e_ea,
    const float* __restrict__ Wpack, const float* __restrict__ Apack,
    float* __restrict__ alpha1) {
    __shared__ float sWp[2048];
    __shared__ float sA[32];
    const int tid = threadIdx.x;
    for (int i = tid; i < 2048; i += 256) sWp[i] = Wpack[i];
    if (tid < 32) sA[tid] = Apack[tid];
    __syncthreads();

    const int e0 = (blockIdx.x * 256 + tid) * 4;
    if (e0 >= E_AUG) return;

    const int4 s4 = *(const int4*)&e_src[e0];
    const int4 d4 = *(const int4*)&e_dst[e0];
    const float4 ea0 = *(const float4*)&e_ea[2 * e0];
    const float4 ea1 = *(const float4*)&e_ea[2 * e0 + 4];

    float u0[4], u1[4], u2[4], u3[4], u4[4], u5[4];
    {
        const int ss[4] = {s4.x, s4.y, s4.z, s4.w};
        const int dd[4] = {d4.x, d4.y, d4.z, d4.w};
        const float ae[8] = {ea0.x, ea0.y, ea0.z, ea0.w, ea1.x, ea1.y, ea1.z, ea1.w};
        #pragma unroll
        for (int j = 0; j < 4; ++j) {
            float2 xs = *(const float2*)&x[2 * ss[j]];
            float2 xd = *(const float2*)&x[2 * dd[j]];
            u0[j] = xs.x; u1[j] = xs.y; u2[j] = xd.x; u3[j] = xd.y;
            u4[j] = ae[2 * j]; u5[j] = ae[2 * j + 1];
        }
    }

    float p[4][4];
    #pragma unroll
    for (int h = 0; h < 4; ++h) {
        const float a0 = sA[h * 8], a1 = sA[h * 8 + 1], a2 = sA[h * 8 + 2],
                    a3 = sA[h * 8 + 3], a4 = sA[h * 8 + 4], a5 = sA[h * 8 + 5],
                    a6 = sA[h * 8 + 6];
        #pragma unroll
        for (int j = 0; j < 4; ++j)
            p[h][j] = fmaf(u0[j], a0, fmaf(u1[j], a1, fmaf(u2[j], a2,
                      fmaf(u3[j], a3, fmaf(u4[j], a4, fmaf(u5[j], a5, a6))))));
    }

    for (int c = 0; c < 64; ++c) {
        const float* wp = &sWp[c * 32];
        #pragma unroll
        for (int h = 0; h < 4; ++h) {
            const float4 wa = *(const float4*)&wp[h * 8];
            const float4 wb = *(const float4*)&wp[h * 8 + 4];
            #pragma unroll
            for (int j = 0; j < 4; ++j) {
                float t = fmaf(u0[j], wa.x,
                          fmaf(u1[j], wa.y,
                          fmaf(u2[j], wa.z,
                          fmaf(u3[j], wa.w,
                          fmaf(u4[j], wb.x,
                          fmaf(u5[j], wb.y, wb.z))))));
                p[h][j] = fmaf(fabsf(t), wb.w, p[h][j]);
            }
        }
    }

    #pragma unroll
    for (int h = 0; h < 4; ++h)
        *(float4*)&alpha1[h * E_AUG + e0] = make_float4(p[h][0], p[h][1], p[h][2], p[h][3]);
}

// ---------------- Layer 1: online softmax, thread per (node,head) ----------------

__global__ __launch_bounds__(256) void l1_softmax_kernel(
    const float* __restrict__ x, const int* __restrict__ offs,
    const int* __restrict__ e_src, const float* __restrict__ alpha1,
    float* __restrict__ Sbuf) {
    int t = blockIdx.x * 256 + threadIdx.x;
    if (t >= 4 * N_NODES) return;
    int n = t >> 2, h = t & 3;
    int beg = offs[n], end = offs[n + 1];
    const float* ap = alpha1 + (size_t)h * E_AUG;

    float amax = -1e30f, den = 0.0f, s1 = 0.0f, s2 = 0.0f;
    for (int e = beg; e < end; ++e) {
        float lg = ap[e];
        int s = e_src[e];
        float2 xs = *(const float2*)&x[2 * s];
        float m = fmaxf(amax, lg);
        float sc = __expf(amax - m);
        float w = __expf(lg - m);
        den = fmaf(den, sc, w);
        s1 = fmaf(s1, sc, w * xs.x);
        s2 = fmaf(s2, sc, w * xs.y);
        amax = m;
    }
    float inv = 1.0f / (den + 1e-16f);
    Sbuf[n * 8 + h] = s1 * inv;
    Sbuf[n * 8 + 4 + h] = s2 * inv;
}

// ---------------- Layer 1 output + layer 2 projections: bf16 MFMA ----------------
// Per block: 64 nodes, full K=256, N=128 (W2l|W2r).
// h tile built in LDS (bf16, XOR-swizzled); B fragments in registers (same for all blocks).
// A layout: m=lane&15, k=(lane>>4)*8+i ; B: n=lane&15, k=(lane>>4)*8+i ;
// D: col=lane&15, row=(lane>>4)*4+reg (verified).

__global__ __launch_bounds__(256) void l1out_mfma_kernel(
    const float* __restrict__ Sbuf, const float4* __restrict__ wpk4,
    const ushort16* __restrict__ Wt,
    const float* __restrict__ b2l, const float* __restrict__ b2r,
    ushort16* __restrict__ xl2b, ushort16* __restrict__ xr2b) {
    __shared__ short hlds[64 * 256];    // 32 KB bf16 h tile
    __shared__ float4 swpk[256];        // 4 KB build coeffs
    const int tid = threadIdx.x;
    const int n0 = blockIdx.x * 64;
    const int lane = tid & 63, w = tid >> 6;

    // ---- B fragments: 2 col-tiles x 8 k-blocks, registers for whole kernel ----
    short8v bfrag[2][8];
    {
        const int bc = w * 32 + (lane & 15);
        const int k0 = (lane >> 4) * 8;
        #pragma unroll
        for (int ct = 0; ct < 2; ++ct)
            #pragma unroll
            for (int kb = 0; kb < 8; ++kb)
                bfrag[ct][kb] = *(const short8v*)&Wt[(size_t)(bc + ct * 16) * 256 + kb * 32 + k0];
    }

    swpk[tid] = wpk4[tid];
    __syncthreads();

    // ---- build h tile: thread -> (node n, head kseg) ----
    {
        const int n = tid >> 2, head = tid & 3, kseg = head * 64;
        const int node = n0 + n;
        float S1 = 0.0f, S2 = 0.0f;
        if (node < N_NODES) {
            S1 = Sbuf[node * 8 + head];
            S2 = Sbuf[node * 8 + 4 + head];
        }
        const int swz = (n & 7) << 3;
        for (int i = 0; i < 8; ++i) {
            short8v hv;
            #pragma unroll
            for (int j = 0; j < 8; ++j) {
                float4 wv = swpk[kseg + i * 8 + j];
                float g = fmaf(wv.x, S1, fmaf(wv.y, S2, wv.z));
                g = g > 0.0f ? g : (__expf(g) - 1.0f);
                hv[j] = (short)f2bf(g);
            }
            *(short8v*)&hlds[(n * 256 + kseg + i * 8) ^ swz] = hv;
        }
    }
    __syncthreads();

    // ---- MFMA: 4 row-tiles x 2 col-tiles x 8 k-blocks ----
    f32x4 acc[4][2];
    #pragma unroll
    for (int rt = 0; rt < 4; ++rt)
        #pragma unroll
        for (int ct = 0; ct < 2; ++ct)
            acc[rt][ct] = (f32x4){0.0f, 0.0f, 0.0f, 0.0f};

    const int arow = lane & 15, ak0 = (lane >> 4) * 8;
    #pragma unroll
    for (int rt = 0; rt < 4; ++rt) {
        const int n = rt * 16 + arow;
        const int swz = (n & 7) << 3;
        #pragma unroll
        for (int kb = 0; kb < 8; ++kb) {
            short8v a = *(const short8v*)&hlds[(n * 256 + kb * 32 + ak0) ^ swz];
            acc[rt][0] = __builtin_amdgcn_mfma_f32_16x16x32_bf16(a, bfrag[0][kb], acc[rt][0], 0, 0, 0);
            acc[rt][1] = __builtin_amdgcn_mfma_f32_16x16x32_bf16(a, bfrag[1][kb], acc[rt][1], 0, 0, 0);
        }
    }

    // ---- epilogue: bf16 store ----
    #pragma unroll
    for (int ct = 0; ct < 2; ++ct) {
        const int c = w * 32 + ct * 16 + (lane & 15);
        const bool isL = (c < 64);
        const int cc = isL ? c : c - 64;
        const float bias = isL ? b2l[cc] : b2r[cc];
        ushort16* dst = isL ? xl2b : xr2b;
        #pragma unroll
        for (int rt = 0; rt < 4; ++rt)
            #pragma unroll
            for (int r = 0; r < 4; ++r) {
                int node = n0 + rt * 16 + (lane >> 4) * 4 + r;
                if (node < N_NODES) dst[node * 64 + cc] = f2bf(acc[rt][ct][r] + bias);
            }
    }
}

// ---------------- Layer 2 logits: 4 edges per wave, 16-lane dot ----------------

__global__ __launch_bounds__(256) void l2_logit_kernel(
    const ushort16* __restrict__ xl2b, const ushort16* __restrict__ xr2b,
    const int* __restrict__ e_src, const int* __restrict__ e_dst,
    const float* __restrict__ e_ea,
    const float* __restrict__ W2e, const float* __restrict__ att2,
    float* __restrict__ alpha2) {
    __shared__ float sWe[128], satt[64];
    const int tid = threadIdx.x;
    if (tid < 128) sWe[tid] = W2e[tid];
    if (tid < 64) satt[tid] = att2[tid];
    __syncthreads();

    const int lane = tid & 63, w = tid >> 6;
    const int e = blockIdx.x * 16 + w * 4 + (lane >> 4);   // E_AUG % 16 == 0

    const int s = e_src[e], d = e_dst[e];
    const float2 ae = *(const float2*)&e_ea[2 * e];
    const int cl = lane & 15;

    float acc = 0.0f;
    #pragma unroll
    for (int q = 0; q < 4; ++q) {
        const int c = cl + q * 16;
        const float xl = bf2f(xl2b[s * 64 + c]);
        const float xr = bf2f(xr2b[d * 64 + c]);
        float t = xl + xr + fmaf(ae.x, sWe[c], ae.y * sWe[64 + c]);
        t = t > 0.0f ? t : 0.2f * t;
        acc = fmaf(t, satt[c], acc);
    }
    #pragma unroll
    for (int off = 8; off; off >>= 1) acc += __shfl_xor(acc, off);
    if (cl == 0) alpha2[e] = acc;
}

// ---------------- Layer 2 aggregation: wave per node, no shuffles ----------------

__global__ __launch_bounds__(256) void l2_aggr_kernel(
    const ushort16* __restrict__ xl2b, const int* __restrict__ offs,
    const int* __restrict__ e_src, const float* __restrict__ alpha2,
    float* __restrict__ pblock) {
    __shared__ float sp[4][64];
    const int tid = threadIdx.x;
    const int l = tid & 63, w = tid >> 6;
    const int n = blockIdx.x * 4 + w;
    const int beg = offs[n], end = offs[n + 1];

    float amax = -1e30f, den = 0.0f, acc = 0.0f;
    int e = beg;
    for (; e + 4 <= end; e += 4) {
        const float4 a4 = *(const float4*)&alpha2[e];
        const int s0 = e_src[e], s1 = e_src[e + 1], s2 = e_src[e + 2], s3 = e_src[e + 3];
        const float xl0 = bf2f(xl2b[s0 * 64 + l]);
        const float xl1 = bf2f(xl2b[s1 * 64 + l]);
        const float xl2 = bf2f(xl2b[s2 * 64 + l]);
        const float xl3 = bf2f(xl2b[s3 * 64 + l]);
        const float mnew = fmaxf(fmaxf(amax, fmaxf(a4.x, a4.y)), fmaxf(a4.z, a4.w));
        const float sc = __expf(amax - mnew);
        const float w0 = __expf(a4.x - mnew), w1 = __expf(a4.y - mnew);
        const float w2 = __expf(a4.z - mnew), w3 = __expf(a4.w - mnew);
        den = fmaf(den, sc, (w0 + w1) + (w2 + w3));
        acc = fmaf(acc, sc, fmaf(w0, xl0, fmaf(w1, xl1, fmaf(w2, xl2, w3 * xl3))));
        amax = mnew;
    }
    for (; e < end; ++e) {
        const float a = alpha2[e];
        const int s = e_src[e];
        const float xl = bf2f(xl2b[s * 64 + l]);
        const float mnew = fmaxf(amax, a);
        const float sc = __expf(amax - mnew);
        const float ww = __expf(a - mnew);
        den = fmaf(den, sc, ww);
        acc = fmaf(acc, sc, ww * xl);
        amax = mnew;
    }
    sp[w][l] = acc / (den + 1e-16f);
    __syncthreads();
    if (tid < 64) {
        float v = sp[0][l] + sp[1][l] + sp[2][l] + sp[3][l];
        pblock[blockIdx.x * 64 + l] = v;
    }
}

// ---------------- final pool ----------------

__global__ __launch_bounds__(256) void pool_final_kernel(const float* __restrict__ pblock,
                                                         const float* __restrict__ bias2,
                                                         float* __restrict__ d_out) {
    __shared__ float s[256];
    int tid = threadIdx.x;
    int l = tid & 63, q = tid >> 6;
    float local = 0.0f;
    for (int r = blockIdx.x * 4 + q; r < 12500; r += 64 * 4)
        local += pblock[r * 64 + l];
    s[tid] = local;
    __syncthreads();
    if (tid < 64) {
        float v = s[tid] + s[tid + 64] + s[tid + 128] + s[tid + 192];
        atomicAdd(&d_out[tid], v * (1.0f / N_NODES));
        if (blockIdx.x == 0) atomicAdd(&d_out[tid], bias2[tid]);
    }
}

// ---------------- Host launch ----------------

extern "C" void kernel_launch(void* const* d_in, const int* in_sizes, int n_in,
                              void* d_out, int out_size, void* d_ws, size_t ws_size,
                              hipStream_t stream) {
    const float* x     = (const float*)d_in[0];
    const float* eattr = (const float*)d_in[1];
    const float* W1l   = (const float*)d_in[2];
    const float* b1l   = (const float*)d_in[3];
    const float* W1r   = (const float*)d_in[4];
    const float* b1r   = (const float*)d_in[5];
    const float* W1e   = (const float*)d_in[6];
    const float* att1  = (const float*)d_in[7];
    const float* bias1 = (const float*)d_in[8];
    const float* W2l   = (const float*)d_in[9];
    const float* b2l   = (const float*)d_in[10];
    const float* W2r   = (const float*)d_in[11];
    const float* b2r   = (const float*)d_in[12];
    const float* W2e   = (const float*)d_in[13];
    const float* att2  = (const float*)d_in[14];
    const float* bias2 = (const float*)d_in[15];
    const int*   ei    = (const int*)d_in[16];
    float* out = (float*)d_out;

    char* p = (char*)d_ws;
    auto alloc = [&](size_t bytes) -> void* {
        void* r = (void*)p;
        p += (bytes + 255) & ~(size_t)255;
        return r;
    };
    int*   deg    = (int*)alloc(N_NODES * 4);
    int*   cnt    = (int*)alloc(N_NODES * 4);
    float* lsum   = (float*)alloc(N_NODES * 2 * 4);
    size_t zlen   = (size_t)((char*)lsum - (char*)deg) + ((N_NODES * 2 * 4 + 255) & ~(size_t)255);
    int*   offs   = (int*)alloc((N_NODES + 1) * 4);
    int*   bsum   = (int*)alloc(256 * 4);
    int*   e_src  = (int*)alloc(E_AUG * 4);
    int*   e_dst  = (int*)alloc(E_AUG * 4);
    float* e_ea   = (float*)alloc((size_t)E_AUG * 2 * 4);
    float* alpha1 = (float*)alloc((size_t)E_AUG * 4 * 4);
    float* alpha2 = (float*)alloc((size_t)E_AUG * 4);
    float* Sbuf   = (float*)alloc((size_t)N_NODES * 8 * 4);
    float* Wpack  = (float*)alloc(256 * 8 * 4);
    float* Apack  = (float*)alloc(32 * 4);
    float4* wpk4  = (float4*)alloc(256 * 16);
    ushort16* Wt  = (ushort16*)alloc(128 * 256 * 2);
    ushort16* xl2b = (ushort16*)alloc((size_t)N_NODES * C2 * 2);
    ushort16* xr2b = (ushort16*)alloc((size_t)N_NODES * C2 * 2);
    float* pblock = (float*)alloc((size_t)12500 * 64 * 4);

    hipMemsetAsync(deg, 0, zlen, stream);
    hipMemsetAsync(d_out, 0, 64 * 4, stream);

    pack_kernel<<<128, 256, 0, stream>>>(W1l, b1l, W1r, b1r, W1e, att1, bias1, W2l, W2r,
                                         Wpack, Apack, wpk4, Wt);

    deg_loop_kernel<<<(N_EDGES + 255) / 256, 256, 0, stream>>>(ei, eattr, deg, lsum);
    int nb = (N_NODES + 255) / 256;   // 196
    scan1_kernel<<<nb, 256, 0, stream>>>(deg, offs, bsum);
    scan23_kernel<<<nb, 256, 0, stream>>>(offs, bsum, nb);
    scatter_kernel<<<(E_AUG + 255) / 256, 256, 0, stream>>>(ei, eattr, deg, lsum, offs, cnt,
                                                            e_src, e_dst, e_ea);

    l1_alpha_kernel<<<(E_AUG / 4 + 255) / 256, 256, 0, stream>>>(x, e_src, e_dst, e_ea,
                                                                 Wpack, Apack, alpha1);

    l1_softmax_kernel<<<(4 * N_NODES + 255) / 256, 256, 0, stream>>>(x, offs, e_src,
                                                                     alpha1, Sbuf);

    l1out_mfma_kernel<<<(N_NODES + 63) / 64, 256, 0, stream>>>(Sbuf, wpk4, Wt,
                                                               b2l, b2r, xl2b, xr2b);

    l2_logit_kernel<<<E_AUG / 16, 256, 0, stream>>>(xl2b, xr2b, e_src, e_dst, e_ea,
                                                    W2e, att2, alpha2);

    l2_aggr_kernel<<<N_NODES / 4, 256, 0, stream>>>(xl2b, offs, e_src, alpha2, pblock);

    pool_final_kernel<<<64, 256, 0, stream>>>(pblock, bias2, out);
}

// Round 7
// 251.719 us; speedup vs baseline: 1.5957x; 1.2267x over previous
//
#include <hip/hip_runtime.h>
#include <hip/hip_bf16.h>

#define N_NODES 50000
#define N_EDGES 500000
#define E_AUG   (N_EDGES + N_NODES)   // 550000 (divisible by 16)
#define NH1 4
#define HID 64
#define C2  64

typedef unsigned int uint32;
typedef unsigned short ushort16;
typedef __attribute__((ext_vector_type(8))) short short8v;
typedef __attribute__((ext_vector_type(4))) float f32x4;

__device__ __forceinline__ ushort16 f2bf(float f) {
    union { float f; uint32 u; } v; v.f = f;
    uint32 u = v.u + (0x7FFFu + ((v.u >> 16) & 1u));   // RNE
    return (ushort16)(u >> 16);
}
__device__ __forceinline__ float bf2f(ushort16 h) {
    union { uint32 u; float f; } v; v.u = ((uint32)h) << 16;
    return v.f;
}

// ---------------- fused pack + degree histogram ----------------
// blocks [0,128): weight packing; blocks [128,...): int histogram (4 edges/thread)

#define PACK_BLOCKS 128
#define HIST_BLOCKS ((N_EDGES / 4 + 255) / 256)   // 489

__global__ void deg_pack_kernel(const int* __restrict__ ei,
                                const float* __restrict__ W1l, const float* __restrict__ b1l,
                                const float* __restrict__ W1r, const float* __restrict__ b1r,
                                const float* __restrict__ W1e, const float* __restrict__ att1,
                                const float* __restrict__ bias1,
                                const float* __restrict__ W2l, const float* __restrict__ W2r,
                                float* __restrict__ Wpack, float* __restrict__ Apack,
                                float4* __restrict__ wpk4, ushort16* __restrict__ Wt,
                                int* __restrict__ deg) {
    const int tid = threadIdx.x;
    if (blockIdx.x < PACK_BLOCKS) {
        int t = blockIdx.x * 256 + tid;
        if (blockIdx.x == 0) {
            if (tid < 256) {
                int h = tid >> 6, hc = tid;
                float* wp = &Wpack[((tid & 63) * 4 + h) * 8];
                wp[0] = W1l[hc];       wp[1] = W1l[256 + hc];
                wp[2] = W1r[hc];       wp[3] = W1r[256 + hc];
                wp[4] = W1e[hc];       wp[5] = W1e[256 + hc];
                wp[6] = b1l[hc] + b1r[hc];
                wp[7] = 0.4f * att1[hc];
                wpk4[hc] = make_float4(W1l[hc], W1l[256 + hc], b1l[hc] + bias1[hc], 0.0f);
            }
            if (tid < 28) {
                int h = tid / 7, comp = tid % 7;
                float s = 0.0f;
                for (int c = 0; c < 64; ++c) {
                    int hc = h * 64 + c;
                    float m;
                    switch (comp) {
                        case 0: m = W1l[hc]; break;
                        case 1: m = W1l[256 + hc]; break;
                        case 2: m = W1r[hc]; break;
                        case 3: m = W1r[256 + hc]; break;
                        case 4: m = W1e[hc]; break;
                        case 5: m = W1e[256 + hc]; break;
                        default: m = b1l[hc] + b1r[hc]; break;
                    }
                    s += att1[hc] * m;
                }
                Apack[h * 8 + comp] = 0.6f * s;
            }
        }
        if (t < 128 * 256) {
            int c = t & 127, k = t >> 7;
            float w = (c < 64) ? W2l[k * 64 + c] : W2r[k * 64 + (c - 64)];
            Wt[c * 256 + k] = f2bf(w);
        }
    } else {
        const int e0 = ((blockIdx.x - PACK_BLOCKS) * 256 + tid) * 4;
        if (e0 < N_EDGES) {   // N_EDGES % 4 == 0
            const int4 d4 = *(const int4*)&ei[N_EDGES + e0];
            atomicAdd(&deg[d4.x], 1);
            atomicAdd(&deg[d4.y], 1);
            atomicAdd(&deg[d4.z], 1);
            atomicAdd(&deg[d4.w], 1);
        }
    }
}

// ---------------- CSR scans ----------------

__global__ void scan1_kernel(const int* __restrict__ deg, int* __restrict__ offs,
                             int* __restrict__ bsum) {
    __shared__ int s[256];
    int tid = threadIdx.x;
    int i = blockIdx.x * 256 + tid;
    int v = (i < N_NODES) ? (deg[i] + 1) : 0;   // +1 reserved self-loop slot
    s[tid] = v;
    __syncthreads();
    for (int off = 1; off < 256; off <<= 1) {
        int t = (tid >= off) ? s[tid - off] : 0;
        __syncthreads();
        s[tid] += t;
        __syncthreads();
    }
    if (i < N_NODES) offs[i + 1] = s[tid];
    if (tid == 255) bsum[blockIdx.x] = s[255];
}

__global__ void scan23_kernel(int* __restrict__ offs, const int* __restrict__ bsum, int nb) {
    __shared__ int s[256];
    int tid = threadIdx.x;
    int b = blockIdx.x;
    s[tid] = (tid < nb && tid < b) ? bsum[tid] : 0;
    __syncthreads();
    for (int off = 128; off; off >>= 1) {
        if (tid < off) s[tid] += s[tid + off];
        __syncthreads();
    }
    int base = s[0];
    int i = b * 256 + tid;
    if (i < N_NODES) offs[i + 1] += base;
    if (i == 0) offs[0] = 0;
}

// ---------------- scatter (real edges; slot offs[d] reserved for self-loop) ----

__global__ void scatter_kernel(const int* __restrict__ ei, const float* __restrict__ ea,
                               const int* __restrict__ offs, int* __restrict__ cnt,
                               int* __restrict__ e_src, int* __restrict__ e_dst,
                               float* __restrict__ e_ea) {
    int e = blockIdx.x * 256 + threadIdx.x;
    if (e >= N_EDGES) return;
    int s = ei[e], d = ei[N_EDGES + e];
    float a0 = ea[2 * e + 0], a1 = ea[2 * e + 1];
    int pos = offs[d] + 1 + atomicAdd(&cnt[d], 1);
    e_src[pos] = s;
    e_dst[pos] = d;
    e_ea[2 * pos + 0] = a0;
    e_ea[2 * pos + 1] = a1;
}

// ---------------- self-loop fill: mean edge_attr over node's real edges ----------

__global__ void loop_fill_kernel(const int* __restrict__ offs,
                                 int* __restrict__ e_src, int* __restrict__ e_dst,
                                 float* __restrict__ e_ea) {
    int n = blockIdx.x * 256 + threadIdx.x;
    if (n >= N_NODES) return;
    int beg = offs[n], end = offs[n + 1];
    float s0 = 0.0f, s1 = 0.0f;
    for (int e = beg + 1; e < end; ++e) {
        s0 += e_ea[2 * e + 0];
        s1 += e_ea[2 * e + 1];
    }
    float inv = 1.0f / (float)max(end - beg - 1, 1);
    e_src[beg] = n;
    e_dst[beg] = n;
    e_ea[2 * beg + 0] = s0 * inv;
    e_ea[2 * beg + 1] = s1 * inv;
}

// ---------------- Layer 1 alpha: edge-parallel, 4 edges/thread ----------------

__global__ __launch_bounds__(256) void l1_alpha_kernel(
    const float* __restrict__ x, const int* __restrict__ e_src,
    const int* __restrict__ e_dst, const float* __restrict__ e_ea,
    const float* __restrict__ Wpack, const float* __restrict__ Apack,
    float* __restrict__ alpha1) {
    __shared__ float sWp[2048];
    __shared__ float sA[32];
    const int tid = threadIdx.x;
    for (int i = tid; i < 2048; i += 256) sWp[i] = Wpack[i];
    if (tid < 32) sA[tid] = Apack[tid];
    __syncthreads();

    const int e0 = (blockIdx.x * 256 + tid) * 4;
    if (e0 >= E_AUG) return;

    const int4 s4 = *(const int4*)&e_src[e0];
    const int4 d4 = *(const int4*)&e_dst[e0];
    const float4 ea0 = *(const float4*)&e_ea[2 * e0];
    const float4 ea1 = *(const float4*)&e_ea[2 * e0 + 4];

    float u0[4], u1[4], u2[4], u3[4], u4[4], u5[4];
    {
        const int ss[4] = {s4.x, s4.y, s4.z, s4.w};
        const int dd[4] = {d4.x, d4.y, d4.z, d4.w};
        const float ae[8] = {ea0.x, ea0.y, ea0.z, ea0.w, ea1.x, ea1.y, ea1.z, ea1.w};
        #pragma unroll
        for (int j = 0; j < 4; ++j) {
            float2 xs = *(const float2*)&x[2 * ss[j]];
            float2 xd = *(const float2*)&x[2 * dd[j]];
            u0[j] = xs.x; u1[j] = xs.y; u2[j] = xd.x; u3[j] = xd.y;
            u4[j] = ae[2 * j]; u5[j] = ae[2 * j + 1];
        }
    }

    float p[4][4];
    #pragma unroll
    for (int h = 0; h < 4; ++h) {
        const float a0 = sA[h * 8], a1 = sA[h * 8 + 1], a2 = sA[h * 8 + 2],
                    a3 = sA[h * 8 + 3], a4 = sA[h * 8 + 4], a5 = sA[h * 8 + 5],
                    a6 = sA[h * 8 + 6];
        #pragma unroll
        for (int j = 0; j < 4; ++j)
            p[h][j] = fmaf(u0[j], a0, fmaf(u1[j], a1, fmaf(u2[j], a2,
                      fmaf(u3[j], a3, fmaf(u4[j], a4, fmaf(u5[j], a5, a6))))));
    }

    for (int c = 0; c < 64; ++c) {
        const float* wp = &sWp[c * 32];
        #pragma unroll
        for (int h = 0; h < 4; ++h) {
            const float4 wa = *(const float4*)&wp[h * 8];
            const float4 wb = *(const float4*)&wp[h * 8 + 4];
            #pragma unroll
            for (int j = 0; j < 4; ++j) {
                float t = fmaf(u0[j], wa.x,
                          fmaf(u1[j], wa.y,
                          fmaf(u2[j], wa.z,
                          fmaf(u3[j], wa.w,
                          fmaf(u4[j], wb.x,
                          fmaf(u5[j], wb.y, wb.z))))));
                p[h][j] = fmaf(fabsf(t), wb.w, p[h][j]);
            }
        }
    }

    #pragma unroll
    for (int h = 0; h < 4; ++h)
        *(float4*)&alpha1[h * E_AUG + e0] = make_float4(p[h][0], p[h][1], p[h][2], p[h][3]);
}

// ---------------- Fused: l1 softmax + h build + bf16 MFMA projections ----------------
// Phase 0: thread (node=tid>>2, head=tid&3) runs online softmax -> S1,S2 in regs.
// Phase 1: same thread builds its h slice (64 bf16) into swizzled LDS.
// Phase 2: MFMA 64x256 @ 256x128 -> xl2b|xr2b bf16.

__global__ __launch_bounds__(256) void l1out_fused_kernel(
    const float* __restrict__ x, const int* __restrict__ offs,
    const int* __restrict__ e_src, const float* __restrict__ alpha1,
    const float4* __restrict__ wpk4, const ushort16* __restrict__ Wt,
    const float* __restrict__ b2l, const float* __restrict__ b2r,
    ushort16* __restrict__ xl2b, ushort16* __restrict__ xr2b) {
    __shared__ short hlds[64 * 256];    // 32 KB bf16 h tile
    __shared__ float4 swpk[256];        // 4 KB build coeffs
    const int tid = threadIdx.x;
    const int n0 = blockIdx.x * 64;
    const int lane = tid & 63, w = tid >> 6;

    swpk[tid] = wpk4[tid];

    // ---- phase 0: online softmax for (node, head) ----
    const int nl = tid >> 2, head = tid & 3;
    const int node = n0 + nl;
    float S1 = 0.0f, S2 = 0.0f;
    if (node < N_NODES) {
        const int beg = offs[node], end = offs[node + 1];
        const float* ap = alpha1 + (size_t)head * E_AUG;
        float amax = -1e30f, den = 0.0f, s1 = 0.0f, s2 = 0.0f;
        for (int e = beg; e < end; ++e) {
            float lg = ap[e];
            int s = e_src[e];
            float2 xs = *(const float2*)&x[2 * s];
            float m = fmaxf(amax, lg);
            float sc = __expf(amax - m);
            float wt = __expf(lg - m);
            den = fmaf(den, sc, wt);
            s1 = fmaf(s1, sc, wt * xs.x);
            s2 = fmaf(s2, sc, wt * xs.y);
            amax = m;
        }
        float inv = 1.0f / (den + 1e-16f);
        S1 = s1 * inv;
        S2 = s2 * inv;
    }
    __syncthreads();   // swpk ready (and no LDS hazard with phase 1)

    // ---- phase 1: build h slice (head segment of 64 channels) ----
    {
        const int kseg = head * 64;
        const int swz = (nl & 7) << 3;
        for (int i = 0; i < 8; ++i) {
            short8v hv;
            #pragma unroll
            for (int j = 0; j < 8; ++j) {
                float4 wv = swpk[kseg + i * 8 + j];
                float g = fmaf(wv.x, S1, fmaf(wv.y, S2, wv.z));
                g = g > 0.0f ? g : (__expf(g) - 1.0f);
                hv[j] = (short)f2bf(g);
            }
            *(short8v*)&hlds[(nl * 256 + kseg + i * 8) ^ swz] = hv;
        }
    }

    // ---- B fragments (after the reg-heavy softmax loop) ----
    short8v bfrag[2][8];
    {
        const int bc = w * 32 + (lane & 15);
        const int k0 = (lane >> 4) * 8;
        #pragma unroll
        for (int ct = 0; ct < 2; ++ct)
            #pragma unroll
            for (int kb = 0; kb < 8; ++kb)
                bfrag[ct][kb] = *(const short8v*)&Wt[(size_t)(bc + ct * 16) * 256 + kb * 32 + k0];
    }
    __syncthreads();

    // ---- phase 2: MFMA 4 row-tiles x 2 col-tiles x 8 k-blocks ----
    f32x4 acc[4][2];
    #pragma unroll
    for (int rt = 0; rt < 4; ++rt)
        #pragma unroll
        for (int ct = 0; ct < 2; ++ct)
            acc[rt][ct] = (f32x4){0.0f, 0.0f, 0.0f, 0.0f};

    const int arow = lane & 15, ak0 = (lane >> 4) * 8;
    #pragma unroll
    for (int rt = 0; rt < 4; ++rt) {
        const int n = rt * 16 + arow;
        const int swz = (n & 7) << 3;
        #pragma unroll
        for (int kb = 0; kb < 8; ++kb) {
            short8v a = *(const short8v*)&hlds[(n * 256 + kb * 32 + ak0) ^ swz];
            acc[rt][0] = __builtin_amdgcn_mfma_f32_16x16x32_bf16(a, bfrag[0][kb], acc[rt][0], 0, 0, 0);
            acc[rt][1] = __builtin_amdgcn_mfma_f32_16x16x32_bf16(a, bfrag[1][kb], acc[rt][1], 0, 0, 0);
        }
    }

    // ---- epilogue: bf16 store ----
    #pragma unroll
    for (int ct = 0; ct < 2; ++ct) {
        const int c = w * 32 + ct * 16 + (lane & 15);
        const bool isL = (c < 64);
        const int cc = isL ? c : c - 64;
        const float bias = isL ? b2l[cc] : b2r[cc];
        ushort16* dst = isL ? xl2b : xr2b;
        #pragma unroll
        for (int rt = 0; rt < 4; ++rt)
            #pragma unroll
            for (int r = 0; r < 4; ++r) {
                int nn = n0 + rt * 16 + (lane >> 4) * 4 + r;
                if (nn < N_NODES) dst[nn * 64 + cc] = f2bf(acc[rt][ct][r] + bias);
            }
    }
}

// ---------------- Layer 2 logits: 4 edges per wave, 16-lane dot ----------------

__global__ __launch_bounds__(256) void l2_logit_kernel(
    const ushort16* __restrict__ xl2b, const ushort16* __restrict__ xr2b,
    const int* __restrict__ e_src, const int* __restrict__ e_dst,
    const float* __restrict__ e_ea,
    const float* __restrict__ W2e, const float* __restrict__ att2,
    float* __restrict__ alpha2) {
    __shared__ float sWe[128], satt[64];
    const int tid = threadIdx.x;
    if (tid < 128) sWe[tid] = W2e[tid];
    if (tid < 64) satt[tid] = att2[tid];
    __syncthreads();

    const int lane = tid & 63, w = tid >> 6;
    const int e = blockIdx.x * 16 + w * 4 + (lane >> 4);   // E_AUG % 16 == 0

    const int s = e_src[e], d = e_dst[e];
    const float2 ae = *(const float2*)&e_ea[2 * e];
    const int cl = lane & 15;

    float acc = 0.0f;
    #pragma unroll
    for (int q = 0; q < 4; ++q) {
        const int c = cl + q * 16;
        const float xl = bf2f(xl2b[s * 64 + c]);
        const float xr = bf2f(xr2b[d * 64 + c]);
        float t = xl + xr + fmaf(ae.x, sWe[c], ae.y * sWe[64 + c]);
        t = t > 0.0f ? t : 0.2f * t;
        acc = fmaf(t, satt[c], acc);
    }
    #pragma unroll
    for (int off = 8; off; off >>= 1) acc += __shfl_xor(acc, off);
    if (cl == 0) alpha2[e] = acc;
}

// ---------------- Layer 2 aggregation: wave per node, no shuffles ----------------

__global__ __launch_bounds__(256) void l2_aggr_kernel(
    const ushort16* __restrict__ xl2b, const int* __restrict__ offs,
    const int* __restrict__ e_src, const float* __restrict__ alpha2,
    float* __restrict__ pblock) {
    __shared__ float sp[4][64];
    const int tid = threadIdx.x;
    const int l = tid & 63, w = tid >> 6;
    const int n = blockIdx.x * 4 + w;
    const int beg = offs[n], end = offs[n + 1];

    float amax = -1e30f, den = 0.0f, acc = 0.0f;
    int e = beg;
    for (; e + 4 <= end; e += 4) {
        const float4 a4 = *(const float4*)&alpha2[e];
        const int s0 = e_src[e], s1 = e_src[e + 1], s2 = e_src[e + 2], s3 = e_src[e + 3];
        const float xl0 = bf2f(xl2b[s0 * 64 + l]);
        const float xl1 = bf2f(xl2b[s1 * 64 + l]);
        const float xl2 = bf2f(xl2b[s2 * 64 + l]);
        const float xl3 = bf2f(xl2b[s3 * 64 + l]);
        const float mnew = fmaxf(fmaxf(amax, fmaxf(a4.x, a4.y)), fmaxf(a4.z, a4.w));
        const float sc = __expf(amax - mnew);
        const float w0 = __expf(a4.x - mnew), w1 = __expf(a4.y - mnew);
        const float w2 = __expf(a4.z - mnew), w3 = __expf(a4.w - mnew);
        den = fmaf(den, sc, (w0 + w1) + (w2 + w3));
        acc = fmaf(acc, sc, fmaf(w0, xl0, fmaf(w1, xl1, fmaf(w2, xl2, w3 * xl3))));
        amax = mnew;
    }
    for (; e < end; ++e) {
        const float a = alpha2[e];
        const int s = e_src[e];
        const float xl = bf2f(xl2b[s * 64 + l]);
        const float mnew = fmaxf(amax, a);
        const float sc = __expf(amax - mnew);
        const float ww = __expf(a - mnew);
        den = fmaf(den, sc, ww);
        acc = fmaf(acc, sc, ww * xl);
        amax = mnew;
    }
    sp[w][l] = acc / (den + 1e-16f);
    __syncthreads();
    if (tid < 64) {
        float v = sp[0][l] + sp[1][l] + sp[2][l] + sp[3][l];
        pblock[blockIdx.x * 64 + l] = v;
    }
}

// ---------------- final pool ----------------

__global__ __launch_bounds__(256) void pool_final_kernel(const float* __restrict__ pblock,
                                                         const float* __restrict__ bias2,
                                                         float* __restrict__ d_out) {
    __shared__ float s[256];
    int tid = threadIdx.x;
    int l = tid & 63, q = tid >> 6;
    float local = 0.0f;
    for (int r = blockIdx.x * 4 + q; r < 12500; r += 64 * 4)
        local += pblock[r * 64 + l];
    s[tid] = local;
    __syncthreads();
    if (tid < 64) {
        float v = s[tid] + s[tid + 64] + s[tid + 128] + s[tid + 192];
        atomicAdd(&d_out[tid], v * (1.0f / N_NODES));
        if (blockIdx.x == 0) atomicAdd(&d_out[tid], bias2[tid]);
    }
}

// ---------------- Host launch ----------------

extern "C" void kernel_launch(void* const* d_in, const int* in_sizes, int n_in,
                              void* d_out, int out_size, void* d_ws, size_t ws_size,
                              hipStream_t stream) {
    const float* x     = (const float*)d_in[0];
    const float* eattr = (const float*)d_in[1];
    const float* W1l   = (const float*)d_in[2];
    const float* b1l   = (const float*)d_in[3];
    const float* W1r   = (const float*)d_in[4];
    const float* b1r   = (const float*)d_in[5];
    const float* W1e   = (const float*)d_in[6];
    const float* att1  = (const float*)d_in[7];
    const float* bias1 = (const float*)d_in[8];
    const float* W2l   = (const float*)d_in[9];
    const float* b2l   = (const float*)d_in[10];
    const float* W2r   = (const float*)d_in[11];
    const float* b2r   = (const float*)d_in[12];
    const float* W2e   = (const float*)d_in[13];
    const float* att2  = (const float*)d_in[14];
    const float* bias2 = (const float*)d_in[15];
    const int*   ei    = (const int*)d_in[16];
    float* out = (float*)d_out;

    char* p = (char*)d_ws;
    auto alloc = [&](size_t bytes) -> void* {
        void* r = (void*)p;
        p += (bytes + 255) & ~(size_t)255;
        return r;
    };
    int*   deg    = (int*)alloc(N_NODES * 4);
    int*   cnt    = (int*)alloc(N_NODES * 4);
    size_t zlen   = (size_t)((char*)cnt - (char*)deg) + ((N_NODES * 4 + 255) & ~(size_t)255);
    int*   offs   = (int*)alloc((N_NODES + 1) * 4);
    int*   bsum   = (int*)alloc(256 * 4);
    int*   e_src  = (int*)alloc(E_AUG * 4);
    int*   e_dst  = (int*)alloc(E_AUG * 4);
    float* e_ea   = (float*)alloc((size_t)E_AUG * 2 * 4);
    float* alpha1 = (float*)alloc((size_t)E_AUG * 4 * 4);
    float* alpha2 = (float*)alloc((size_t)E_AUG * 4);
    float* Wpack  = (float*)alloc(256 * 8 * 4);
    float* Apack  = (float*)alloc(32 * 4);
    float4* wpk4  = (float4*)alloc(256 * 16);
    ushort16* Wt  = (ushort16*)alloc(128 * 256 * 2);
    ushort16* xl2b = (ushort16*)alloc((size_t)N_NODES * C2 * 2);
    ushort16* xr2b = (ushort16*)alloc((size_t)N_NODES * C2 * 2);
    float* pblock = (float*)alloc((size_t)12500 * 64 * 4);

    hipMemsetAsync(deg, 0, zlen, stream);
    hipMemsetAsync(d_out, 0, 64 * 4, stream);

    deg_pack_kernel<<<PACK_BLOCKS + HIST_BLOCKS, 256, 0, stream>>>(
        ei, W1l, b1l, W1r, b1r, W1e, att1, bias1, W2l, W2r,
        Wpack, Apack, wpk4, Wt, deg);

    int nb = (N_NODES + 255) / 256;   // 196
    scan1_kernel<<<nb, 256, 0, stream>>>(deg, offs, bsum);
    scan23_kernel<<<nb, 256, 0, stream>>>(offs, bsum, nb);
    scatter_kernel<<<(N_EDGES + 255) / 256, 256, 0, stream>>>(ei, eattr, offs, cnt,
                                                              e_src, e_dst, e_ea);
    loop_fill_kernel<<<nb, 256, 0, stream>>>(offs, e_src, e_dst, e_ea);

    l1_alpha_kernel<<<(E_AUG / 4 + 255) / 256, 256, 0, stream>>>(x, e_src, e_dst, e_ea,
                                                                 Wpack, Apack, alpha1);

    l1out_fused_kernel<<<(N_NODES + 63) / 64, 256, 0, stream>>>(x, offs, e_src, alpha1,
                                                                wpk4, Wt, b2l, b2r,
                                                                xl2b, xr2b);

    l2_logit_kernel<<<E_AUG / 16, 256, 0, stream>>>(xl2b, xr2b, e_src, e_dst, e_ea,
                                                    W2e, att2, alpha2);

    l2_aggr_kernel<<<N_NODES / 4, 256, 0, stream>>>(xl2b, offs, e_src, alpha2, pblock);

    pool_final_kernel<<<64, 256, 0, stream>>>(pblock, bias2, out);
}